// Round 1
// baseline (1386.992 us; speedup 1.0000x reference)
//
#include <hip/hip_runtime.h>
#include <hip/hip_bf16.h>
#include <cstdint>
#include <cstddef>

#define LRELU(x, s) ((x) > 0.f ? (x) : (s) * (x))

__device__ __forceinline__ unsigned flipf(float f) {
  unsigned u = __float_as_uint(f);
  return (u & 0x80000000u) ? ~u : (u | 0x80000000u);
}
__device__ __forceinline__ float unflipf(unsigned v) {
  unsigned u = (v & 0x80000000u) ? (v ^ 0x80000000u) : ~v;
  return __uint_as_float(u);
}

// ---------------- fp32 tiled GEMM: C[M,N] = A[M,K] @ B[K,N] ----------------
// 64x64 block tile, BK=16, 256 threads, 4x4 microtile per thread.
__global__ __launch_bounds__(256) void gemm_f32(
    const float* __restrict__ A, const float* __restrict__ B, float* __restrict__ C,
    int M, int K, int N) {
  __shared__ float sA[16][68];  // [k][m], +4 pad kills 4-way conflicts
  __shared__ float sB[16][68];  // [k][n]
  const int tid = threadIdx.x;
  const int tilesN = N >> 6;
  const int bx = blockIdx.x % tilesN;
  const int by = blockIdx.x / tilesN;
  const int lr = tid >> 2;          // A tile row 0..63
  const int lk = (tid & 3) << 2;    // A k offset 0,4,8,12
  const int bkr = tid >> 4;         // B k row 0..15
  const int bn = (tid & 15) << 2;   // B col offset
  const int tx = tid & 15;
  const int ty = tid >> 4;
  const int rowA = by * 64 + lr;
  const float* Ap = A + (size_t)rowA * K;
  const float* Bp = B + (size_t)bx * 64 + bn;

  float4 acc[4];
#pragma unroll
  for (int i = 0; i < 4; i++) acc[i] = make_float4(0.f, 0.f, 0.f, 0.f);

  for (int k0 = 0; k0 < K; k0 += 16) {
    float a0 = 0.f, a1 = 0.f, a2 = 0.f, a3 = 0.f;
    if (rowA < M) {
      const float* p = Ap + k0 + lk;
      if (k0 + lk + 3 < K && ((((uintptr_t)p) & 15) == 0)) {
        const float4 v = *(const float4*)p;
        a0 = v.x; a1 = v.y; a2 = v.z; a3 = v.w;
      } else {
        if (k0 + lk + 0 < K) a0 = p[0];
        if (k0 + lk + 1 < K) a1 = p[1];
        if (k0 + lk + 2 < K) a2 = p[2];
        if (k0 + lk + 3 < K) a3 = p[3];
      }
    }
    float4 bv = make_float4(0.f, 0.f, 0.f, 0.f);
    if (k0 + bkr < K) bv = *(const float4*)(Bp + (size_t)(k0 + bkr) * N);
    __syncthreads();
    sA[lk + 0][lr] = a0; sA[lk + 1][lr] = a1; sA[lk + 2][lr] = a2; sA[lk + 3][lr] = a3;
    *(float4*)&sB[bkr][bn] = bv;
    __syncthreads();
#pragma unroll
    for (int kk = 0; kk < 16; kk++) {
      const float4 b4 = *(const float4*)&sB[kk][tx << 2];
#pragma unroll
      for (int i = 0; i < 4; i++) {
        const float a = sA[kk][(ty << 2) + i];
        acc[i].x += a * b4.x; acc[i].y += a * b4.y;
        acc[i].z += a * b4.z; acc[i].w += a * b4.w;
      }
    }
  }
  const int col = bx * 64 + (tx << 2);
#pragma unroll
  for (int i = 0; i < 4; i++) {
    const int row = by * 64 + (ty << 2) + i;
    if (row < M) *(float4*)(C + (size_t)row * N + col) = acc[i];
  }
}

// ---------------- CSR build ----------------
__global__ void count_deg(const int* __restrict__ dst, int E, int* __restrict__ deg) {
  const int t = blockIdx.x * blockDim.x + threadIdx.x;
  if (t < E) atomicAdd(&deg[dst[t]], 1);
}

// single-block scan: rowptr (inclusive into [i+1]) and cursor (exclusive).
// adds +1 per node for the self-loop.
__global__ void scan_kernel(const int* __restrict__ deg, int* __restrict__ rowptr,
                            int* __restrict__ cursor, int n) {
  __shared__ int sd[256];
  __shared__ int carry_s;
  const int t = threadIdx.x;
  if (t == 0) carry_s = 0;
  __syncthreads();
  for (int base = 0; base < n; base += 256) {
    const int i = base + t;
    const int v = (i < n) ? (deg[i] + 1) : 0;
    sd[t] = v;
    __syncthreads();
    for (int off = 1; off < 256; off <<= 1) {
      int tmp = 0;
      if (t >= off) tmp = sd[t - off];
      __syncthreads();
      sd[t] += tmp;
      __syncthreads();
    }
    const int incl = sd[t] + carry_s;
    if (i < n) { rowptr[i + 1] = incl; cursor[i] = incl - v; }
    if (base == 0 && t == 0) rowptr[0] = 0;
    __syncthreads();
    if (t == 255) carry_s += sd[255];
    __syncthreads();
  }
}

__global__ void scatter_edges(const int* __restrict__ esrc, const int* __restrict__ edst,
                              int E, int Etot, int* __restrict__ cursor,
                              int* __restrict__ csr_src) {
  const int t = blockIdx.x * blockDim.x + threadIdx.x;
  if (t >= Etot) return;
  int s, d;
  if (t < E) { s = esrc[t]; d = edst[t]; } else { s = t - E; d = s; }
  const int pos = atomicAdd(&cursor[d], 1);
  csr_src[pos] = s;
}

// ---------------- attention dot products: a_s[n,h], a_d[n,h] ----------------
__global__ void att_dots(const float* __restrict__ hmat, const float* __restrict__ att_s,
                         const float* __restrict__ att_d, float* __restrict__ a_s,
                         float* __restrict__ a_d, int NH, int H, int C) {
  const int w = blockIdx.x * (blockDim.x >> 6) + (threadIdx.x >> 6);
  const int lane = threadIdx.x & 63;
  if (w >= NH) return;
  const int n = w / H;
  const int h = w - n * H;
  const float* hp = hmat + (size_t)n * H * C + (size_t)h * C;
  const float* asp = att_s + h * C;
  const float* adp = att_d + h * C;
  float ss = 0.f, sd = 0.f;
  for (int c = lane; c < C; c += 64) {
    const float v = hp[c];
    ss += v * asp[c];
    sd += v * adp[c];
  }
  for (int off = 32; off > 0; off >>= 1) {
    ss += __shfl_down(ss, off);
    sd += __shfl_down(sd, off);
  }
  if (lane == 0) { a_s[w] = ss; a_d[w] = sd; }
}

// ---------------- per-edge softmax stats ----------------
__global__ void edge_atomic_max(const int* __restrict__ esrc, const int* __restrict__ edst,
                                int E, int Etot, const float* __restrict__ a_s,
                                const float* __restrict__ a_d, unsigned* __restrict__ m_flip,
                                int H) {
  const int t = blockIdx.x * blockDim.x + threadIdx.x;
  if (t >= Etot * H) return;
  const int e = t / H;
  const int h = t - e * H;
  int s, d;
  if (e < E) { s = esrc[e]; d = edst[e]; } else { s = e - E; d = s; }
  float lg = a_s[s * H + h] + a_d[d * H + h];
  lg = LRELU(lg, 0.2f);
  atomicMax(&m_flip[d * H + h], flipf(lg));
}

__global__ void edge_atomic_sum(const int* __restrict__ esrc, const int* __restrict__ edst,
                                int E, int Etot, const float* __restrict__ a_s,
                                const float* __restrict__ a_d,
                                const unsigned* __restrict__ m_flip,
                                float* __restrict__ den, int H) {
  const int t = blockIdx.x * blockDim.x + threadIdx.x;
  if (t >= Etot * H) return;
  const int e = t / H;
  const int h = t - e * H;
  int s, d;
  if (e < E) { s = esrc[e]; d = edst[e]; } else { s = e - E; d = s; }
  float lg = a_s[s * H + h] + a_d[d * H + h];
  lg = LRELU(lg, 0.2f);
  const float m = unflipf(m_flip[d * H + h]);
  atomicAdd(&den[d * H + h], expf(lg - m));
}

// ---------------- gather aggregate: out[n,:] = act( sum_j alpha_j * h[src_j,:] + bias ) ----
template <int H, int C, int CPT>
__global__ void gat_aggregate(const float* __restrict__ hmat, const int* __restrict__ rowptr,
                              const int* __restrict__ csr_src, const float* __restrict__ a_s,
                              const float* __restrict__ a_d, const unsigned* __restrict__ m_flip,
                              const float* __restrict__ den, const float* __restrict__ bias,
                              float* __restrict__ out, float act_slope) {
  constexpr int HC = H * C;
  constexpr int BD = HC / CPT;
  const int n = blockIdx.x;
  const int tid = threadIdx.x;
  __shared__ int ssrc[32];
  __shared__ float sw[32 * H];
  float ad_n[H], mh[H], invd[H];
#pragma unroll
  for (int h = 0; h < H; h++) {
    ad_n[h] = a_d[n * H + h];
    mh[h] = unflipf(m_flip[n * H + h]);
    invd[h] = 1.f / den[n * H + h];
  }
  const int start = rowptr[n];
  const int end = rowptr[n + 1];
  float acc[CPT];
#pragma unroll
  for (int q = 0; q < CPT; q++) acc[q] = 0.f;

  for (int base = start; base < end; base += 32) {
    const int cnt = min(32, end - base);
    __syncthreads();
    if (tid < cnt) {
      const int s = csr_src[base + tid];
      ssrc[tid] = s;
#pragma unroll
      for (int h = 0; h < H; h++) {
        float lg = a_s[s * H + h] + ad_n[h];
        lg = LRELU(lg, 0.2f);
        sw[tid * H + h] = expf(lg - mh[h]) * invd[h];
      }
    }
    __syncthreads();
    for (int j = 0; j < cnt; j++) {
      const int s = ssrc[j];
      const float* hp = hmat + (size_t)s * HC;
#pragma unroll
      for (int q = 0; q < CPT; q++) {
        const int c = tid + q * BD;
        acc[q] += sw[j * H + (c / C)] * hp[c];
      }
    }
  }
#pragma unroll
  for (int q = 0; q < CPT; q++) {
    const int c = tid + q * BD;
    const float v = acc[q] + bias[c];
    out[(size_t)n * HC + c] = LRELU(v, act_slope);
  }
}

// ---------------- head MLP: 128 -> 16 -> (leaky) 32 -> 2 ----------------
__global__ __launch_bounds__(128) void head_mlp(
    const float* __restrict__ h, const float* __restrict__ pw, const float* __restrict__ pb,
    const float* __restrict__ f1w, const float* __restrict__ f1b,
    const float* __restrict__ f2w, const float* __restrict__ f2b, float* __restrict__ out) {
  const int n = blockIdx.x;
  const int t = threadIdx.x;
  __shared__ float sx[128];
  __shared__ float s1[16];
  __shared__ float s2[32];
  sx[t] = h[(size_t)n * 128 + t];
  __syncthreads();
  if (t < 16) {
    float a = pb[t];
    for (int c = 0; c < 128; c++) a += sx[c] * pw[c * 16 + t];
    s1[t] = a;  // pre_fc has no activation
  }
  __syncthreads();
  if (t < 32) {
    float a = f1b[t];
    for (int c = 0; c < 16; c++) a += s1[c] * f1w[c * 32 + t];
    s2[t] = LRELU(a, 0.15f);
  }
  __syncthreads();
  if (t < 2) {
    float a = f2b[t];
    for (int c = 0; c < 32; c++) a += s2[c] * f2w[c * 2 + t];
    out[(size_t)n * 2 + t] = a;
  }
}

extern "C" void kernel_launch(void* const* d_in, const int* in_sizes, int n_in,
                              void* d_out, int out_size, void* d_ws, size_t ws_size,
                              hipStream_t stream) {
  const float* x   = (const float*)d_in[0];
  const int* ei    = (const int*)d_in[1];
  const float* W1  = (const float*)d_in[2];
  const float* as1 = (const float*)d_in[3];
  const float* ad1 = (const float*)d_in[4];
  const float* b1  = (const float*)d_in[5];
  const float* W2  = (const float*)d_in[6];
  const float* as2 = (const float*)d_in[7];
  const float* ad2 = (const float*)d_in[8];
  const float* b2  = (const float*)d_in[9];
  const float* W3  = (const float*)d_in[10];
  const float* as3 = (const float*)d_in[11];
  const float* ad3 = (const float*)d_in[12];
  const float* b3  = (const float*)d_in[13];
  const float* pw  = (const float*)d_in[14];
  const float* pb  = (const float*)d_in[15];
  const float* f1w = (const float*)d_in[16];
  const float* f1b = (const float*)d_in[17];
  const float* f2w = (const float*)d_in[18];
  const float* f2b = (const float*)d_in[19];
  float* out = (float*)d_out;

  const int N = in_sizes[0] / 1287;   // 20000
  const int E = in_sizes[1] / 2;      // 160000
  const int Etot = E + N;             // 180000
  const int* esrc = ei;
  const int* edst = ei + E;

  char* ws = (char*)d_ws;
  size_t off = 0;
  auto alloc = [&](size_t bytes) -> void* {
    void* p = ws + off;
    off = (off + bytes + 255) & ~(size_t)255;
    return p;
  };
  float* h_buf   = (float*)alloc((size_t)N * 1024 * sizeof(float));
  float* o_buf   = (float*)alloc((size_t)N * 1024 * sizeof(float));
  float* as_buf  = (float*)alloc((size_t)N * 4 * sizeof(float));
  float* ad_buf  = (float*)alloc((size_t)N * 4 * sizeof(float));
  unsigned* m_buf = (unsigned*)alloc((size_t)N * 4 * sizeof(unsigned));
  float* den_buf = (float*)alloc((size_t)N * 4 * sizeof(float));
  int* deg    = (int*)alloc((size_t)N * sizeof(int));
  int* rowptr = (int*)alloc((size_t)(N + 1) * sizeof(int));
  int* cursor = (int*)alloc((size_t)N * sizeof(int));
  int* csr    = (int*)alloc((size_t)Etot * sizeof(int));

  // ---- CSR build (same graph all layers) ----
  hipMemsetAsync(deg, 0, (size_t)N * sizeof(int), stream);
  count_deg<<<(E + 255) / 256, 256, 0, stream>>>(edst, E, deg);
  scan_kernel<<<1, 256, 0, stream>>>(deg, rowptr, cursor, N);
  scatter_edges<<<(Etot + 255) / 256, 256, 0, stream>>>(esrc, edst, E, Etot, cursor, csr);

  const int tilesM = (N + 63) / 64;

  // ---- layer 1: 1287 -> 4x128, concat ----
  {
    const int H = 4, C = 128, HC = 512, K = 1287;
    gemm_f32<<<tilesM * (HC / 64), 256, 0, stream>>>(x, W1, h_buf, N, K, HC);
    const int NH = N * H;
    att_dots<<<(NH + 3) / 4, 256, 0, stream>>>(h_buf, as1, ad1, as_buf, ad_buf, NH, H, C);
    hipMemsetAsync(m_buf, 0, (size_t)NH * sizeof(unsigned), stream);
    hipMemsetAsync(den_buf, 0, (size_t)NH * sizeof(float), stream);
    const int tE = Etot * H;
    edge_atomic_max<<<(tE + 255) / 256, 256, 0, stream>>>(esrc, edst, E, Etot, as_buf, ad_buf, m_buf, H);
    edge_atomic_sum<<<(tE + 255) / 256, 256, 0, stream>>>(esrc, edst, E, Etot, as_buf, ad_buf, m_buf, den_buf, H);
    gat_aggregate<4, 128, 2><<<N, 256, 0, stream>>>(h_buf, rowptr, csr, as_buf, ad_buf,
                                                    m_buf, den_buf, b1, o_buf, 0.15f);
  }
  // ---- layer 2: 512 -> 4x256, concat ----
  {
    const int H = 4, C = 256, HC = 1024, K = 512;
    gemm_f32<<<tilesM * (HC / 64), 256, 0, stream>>>(o_buf, W2, h_buf, N, K, HC);
    const int NH = N * H;
    att_dots<<<(NH + 3) / 4, 256, 0, stream>>>(h_buf, as2, ad2, as_buf, ad_buf, NH, H, C);
    hipMemsetAsync(m_buf, 0, (size_t)NH * sizeof(unsigned), stream);
    hipMemsetAsync(den_buf, 0, (size_t)NH * sizeof(float), stream);
    const int tE = Etot * H;
    edge_atomic_max<<<(tE + 255) / 256, 256, 0, stream>>>(esrc, edst, E, Etot, as_buf, ad_buf, m_buf, H);
    edge_atomic_sum<<<(tE + 255) / 256, 256, 0, stream>>>(esrc, edst, E, Etot, as_buf, ad_buf, m_buf, den_buf, H);
    gat_aggregate<4, 256, 4><<<N, 256, 0, stream>>>(h_buf, rowptr, csr, as_buf, ad_buf,
                                                    m_buf, den_buf, b2, o_buf, 0.15f);
  }
  // ---- layer 3: 1024 -> 128, 1 head, mean(=identity) ----
  {
    const int H = 1, C = 128, HC = 128, K = 1024;
    gemm_f32<<<tilesM * (HC / 64), 256, 0, stream>>>(o_buf, W3, h_buf, N, K, HC);
    const int NH = N * H;
    att_dots<<<(NH + 3) / 4, 256, 0, stream>>>(h_buf, as3, ad3, as_buf, ad_buf, NH, H, C);
    hipMemsetAsync(m_buf, 0, (size_t)NH * sizeof(unsigned), stream);
    hipMemsetAsync(den_buf, 0, (size_t)NH * sizeof(float), stream);
    const int tE = Etot * H;
    edge_atomic_max<<<(tE + 255) / 256, 256, 0, stream>>>(esrc, edst, E, Etot, as_buf, ad_buf, m_buf, H);
    edge_atomic_sum<<<(tE + 255) / 256, 256, 0, stream>>>(esrc, edst, E, Etot, as_buf, ad_buf, m_buf, den_buf, H);
    gat_aggregate<1, 128, 1><<<N, 128, 0, stream>>>(h_buf, rowptr, csr, as_buf, ad_buf,
                                                    m_buf, den_buf, b3, o_buf, 0.15f);
  }
  // ---- head MLP ----
  head_mlp<<<N, 128, 0, stream>>>(o_buf, pw, pb, f1w, f1b, f2w, f2b, out);
}

// Round 2
// 795.633 us; speedup vs baseline: 1.7433x; 1.7433x over previous
//
#include <hip/hip_runtime.h>
#include <hip/hip_bf16.h>
#include <cstdint>
#include <cstddef>

#define LRELU(x, s) ((x) > 0.f ? (x) : (s) * (x))

typedef __attribute__((ext_vector_type(8))) short bf16x8;
typedef __attribute__((ext_vector_type(4))) float f32x4;

__device__ __forceinline__ unsigned flipf(float f) {
  unsigned u = __float_as_uint(f);
  return (u & 0x80000000u) ? ~u : (u | 0x80000000u);
}
__device__ __forceinline__ float unflipf(unsigned v) {
  unsigned u = (v & 0x80000000u) ? (v ^ 0x80000000u) : ~v;
  return __uint_as_float(u);
}

// ---------------- casts ----------------
// fp32 [rows][K] -> bf16 [rows][Kp], zero pad K..Kp
__global__ void cast_pad_rows(const float* __restrict__ in, __hip_bfloat16* __restrict__ out,
                              int rows, int K, int Kp) {
  const long long idx = (long long)blockIdx.x * blockDim.x + threadIdx.x;
  if (idx >= (long long)rows * Kp) return;
  const int r = (int)(idx / Kp);
  const int c = (int)(idx - (long long)r * Kp);
  const float v = (c < K) ? in[(size_t)r * K + c] : 0.f;
  out[idx] = __float2bfloat16(v);
}

// W fp32 [K][Nn] -> Wt bf16 [Nn][Kp] (transposed), zero pad
__global__ void cast_W_T(const float* __restrict__ W, __hip_bfloat16* __restrict__ Wt,
                         int K, int Nn, int Kp) {
  const long long idx = (long long)blockIdx.x * blockDim.x + threadIdx.x;
  if (idx >= (long long)Nn * Kp) return;
  const int n = (int)(idx / Kp);
  const int k = (int)(idx - (long long)n * Kp);
  const float v = (k < K) ? W[(size_t)k * Nn + n] : 0.f;
  Wt[idx] = __float2bfloat16(v);
}

// ---------------- bf16 MFMA GEMM: C[M,N] f32 = A[M,Kp] bf16 @ Bt[N,Kp]^T ----------------
// 128x128 tile, BK=32, 256 threads (4 waves), each wave 64x64 via 4x4 MFMA 16x16x32.
__global__ __launch_bounds__(256) void gemm_bf16(
    const ushort* __restrict__ A, const ushort* __restrict__ Bt, float* __restrict__ C,
    int M, int N, int Kp) {
  constexpr int LDA = 40;  // 32 + 8 pad (80 B stride -> 2-way LDS aliasing only)
  __shared__ ushort sA[128 * LDA];
  __shared__ ushort sB[128 * LDA];
  const int tid = threadIdx.x;
  const int wave = tid >> 6;
  const int lane = tid & 63;
  const int tilesN = N >> 7;
  const int bx = blockIdx.x % tilesN;
  const int by = blockIdx.x / tilesN;
  // staging: thread loads 2 A rows + 2 B rows, 16 B each
  const int srow = tid >> 2;         // 0..63
  const int sseg = (tid & 3) * 8;    // element offset 0,8,16,24
  // wave tile
  const int wrow = (wave >> 1) * 64;
  const int wcol = (wave & 1) * 64;
  const int quad = lane >> 4;
  const int ml = lane & 15;

  const int rA1 = min(by * 128 + srow, M - 1);
  const int rA2 = min(by * 128 + srow + 64, M - 1);
  const int cB1 = bx * 128 + srow;
  const size_t offA1 = (size_t)rA1 * Kp + sseg;
  const size_t offA2 = (size_t)rA2 * Kp + sseg;
  const size_t offB1 = (size_t)cB1 * Kp + sseg;
  const size_t offB2 = (size_t)(cB1 + 64) * Kp + sseg;

  f32x4 acc[4][4];
#pragma unroll
  for (int mi = 0; mi < 4; mi++)
#pragma unroll
    for (int ni = 0; ni < 4; ni++)
#pragma unroll
      for (int e = 0; e < 4; e++) acc[mi][ni][e] = 0.f;

  for (int k0 = 0; k0 < Kp; k0 += 32) {
    const uint4 a1 = *(const uint4*)(A + offA1 + k0);
    const uint4 a2 = *(const uint4*)(A + offA2 + k0);
    const uint4 b1 = *(const uint4*)(Bt + offB1 + k0);
    const uint4 b2 = *(const uint4*)(Bt + offB2 + k0);
    __syncthreads();
    *(uint4*)&sA[srow * LDA + sseg] = a1;
    *(uint4*)&sA[(srow + 64) * LDA + sseg] = a2;
    *(uint4*)&sB[srow * LDA + sseg] = b1;
    *(uint4*)&sB[(srow + 64) * LDA + sseg] = b2;
    __syncthreads();
    bf16x8 af[4], bfr[4];
#pragma unroll
    for (int mi = 0; mi < 4; mi++)
      af[mi] = *(const bf16x8*)&sA[(wrow + mi * 16 + ml) * LDA + quad * 8];
#pragma unroll
    for (int ni = 0; ni < 4; ni++)
      bfr[ni] = *(const bf16x8*)&sB[(wcol + ni * 16 + ml) * LDA + quad * 8];
#pragma unroll
    for (int mi = 0; mi < 4; mi++)
#pragma unroll
      for (int ni = 0; ni < 4; ni++)
        acc[mi][ni] = __builtin_amdgcn_mfma_f32_16x16x32_bf16(af[mi], bfr[ni], acc[mi][ni], 0, 0, 0);
  }

#pragma unroll
  for (int mi = 0; mi < 4; mi++) {
#pragma unroll
    for (int r = 0; r < 4; r++) {
      const int row = by * 128 + wrow + mi * 16 + quad * 4 + r;
      if (row < M) {
#pragma unroll
        for (int ni = 0; ni < 4; ni++) {
          const int col = bx * 128 + wcol + ni * 16 + ml;
          C[(size_t)row * N + col] = acc[mi][ni][r];
        }
      }
    }
  }
}

// ---------------- CSR build ----------------
__global__ void count_deg(const int* __restrict__ dst, int E, int* __restrict__ deg) {
  const int t = blockIdx.x * blockDim.x + threadIdx.x;
  if (t < E) atomicAdd(&deg[dst[t]], 1);
}

__global__ void scan_kernel(const int* __restrict__ deg, int* __restrict__ rowptr,
                            int* __restrict__ cursor, int n) {
  __shared__ int sd[256];
  __shared__ int carry_s;
  const int t = threadIdx.x;
  if (t == 0) carry_s = 0;
  __syncthreads();
  for (int base = 0; base < n; base += 256) {
    const int i = base + t;
    const int v = (i < n) ? (deg[i] + 1) : 0;
    sd[t] = v;
    __syncthreads();
    for (int off = 1; off < 256; off <<= 1) {
      int tmp = 0;
      if (t >= off) tmp = sd[t - off];
      __syncthreads();
      sd[t] += tmp;
      __syncthreads();
    }
    const int incl = sd[t] + carry_s;
    if (i < n) { rowptr[i + 1] = incl; cursor[i] = incl - v; }
    if (base == 0 && t == 0) rowptr[0] = 0;
    __syncthreads();
    if (t == 255) carry_s += sd[255];
    __syncthreads();
  }
}

__global__ void scatter_edges(const int* __restrict__ esrc, const int* __restrict__ edst,
                              int E, int Etot, int* __restrict__ cursor,
                              int* __restrict__ csr_src) {
  const int t = blockIdx.x * blockDim.x + threadIdx.x;
  if (t >= Etot) return;
  int s, d;
  if (t < E) { s = esrc[t]; d = edst[t]; } else { s = t - E; d = s; }
  const int pos = atomicAdd(&cursor[d], 1);
  csr_src[pos] = s;
}

// ---------------- attention dots ----------------
__global__ void att_dots(const float* __restrict__ hmat, const float* __restrict__ att_s,
                         const float* __restrict__ att_d, float* __restrict__ a_s,
                         float* __restrict__ a_d, int NH, int H, int C) {
  const int w = blockIdx.x * (blockDim.x >> 6) + (threadIdx.x >> 6);
  const int lane = threadIdx.x & 63;
  if (w >= NH) return;
  const int n = w / H;
  const int h = w - n * H;
  const float* hp = hmat + (size_t)n * H * C + (size_t)h * C;
  const float* asp = att_s + h * C;
  const float* adp = att_d + h * C;
  float ss = 0.f, sd = 0.f;
  for (int c = lane; c < C; c += 64) {
    const float v = hp[c];
    ss += v * asp[c];
    sd += v * adp[c];
  }
  for (int off = 32; off > 0; off >>= 1) {
    ss += __shfl_down(ss, off);
    sd += __shfl_down(sd, off);
  }
  if (lane == 0) { a_s[w] = ss; a_d[w] = sd; }
}

// ---------------- per-edge softmax stats ----------------
__global__ void edge_atomic_max(const int* __restrict__ esrc, const int* __restrict__ edst,
                                int E, int Etot, const float* __restrict__ a_s,
                                const float* __restrict__ a_d, unsigned* __restrict__ m_flip,
                                int H) {
  const int t = blockIdx.x * blockDim.x + threadIdx.x;
  if (t >= Etot * H) return;
  const int e = t / H;
  const int h = t - e * H;
  int s, d;
  if (e < E) { s = esrc[e]; d = edst[e]; } else { s = e - E; d = s; }
  float lg = a_s[s * H + h] + a_d[d * H + h];
  lg = LRELU(lg, 0.2f);
  atomicMax(&m_flip[d * H + h], flipf(lg));
}

__global__ void edge_atomic_sum(const int* __restrict__ esrc, const int* __restrict__ edst,
                                int E, int Etot, const float* __restrict__ a_s,
                                const float* __restrict__ a_d,
                                const unsigned* __restrict__ m_flip,
                                float* __restrict__ den, int H) {
  const int t = blockIdx.x * blockDim.x + threadIdx.x;
  if (t >= Etot * H) return;
  const int e = t / H;
  const int h = t - e * H;
  int s, d;
  if (e < E) { s = esrc[e]; d = edst[e]; } else { s = e - E; d = s; }
  float lg = a_s[s * H + h] + a_d[d * H + h];
  lg = LRELU(lg, 0.2f);
  const float m = unflipf(m_flip[d * H + h]);
  atomicAdd(&den[d * H + h], expf(lg - m));
}

// ---------------- gather aggregate ----------------
// BOUT: write bf16 (next layer's GEMM input); else fp32.
template <int H, int C, int CPT, bool BOUT>
__global__ void gat_aggregate(const float* __restrict__ hmat, const int* __restrict__ rowptr,
                              const int* __restrict__ csr_src, const float* __restrict__ a_s,
                              const float* __restrict__ a_d, const unsigned* __restrict__ m_flip,
                              const float* __restrict__ den, const float* __restrict__ bias,
                              float* __restrict__ out, __hip_bfloat16* __restrict__ outb,
                              float act_slope) {
  constexpr int HC = H * C;
  constexpr int BD = HC / CPT;
  const int n = blockIdx.x;
  const int tid = threadIdx.x;
  __shared__ int ssrc[32];
  __shared__ float sw[32 * H];
  float ad_n[H], mh[H], invd[H];
#pragma unroll
  for (int h = 0; h < H; h++) {
    ad_n[h] = a_d[n * H + h];
    mh[h] = unflipf(m_flip[n * H + h]);
    invd[h] = 1.f / den[n * H + h];
  }
  const int start = rowptr[n];
  const int end = rowptr[n + 1];
  float acc[CPT];
#pragma unroll
  for (int q = 0; q < CPT; q++) acc[q] = 0.f;

  for (int base = start; base < end; base += 32) {
    const int cnt = min(32, end - base);
    __syncthreads();
    if (tid < cnt) {
      const int s = csr_src[base + tid];
      ssrc[tid] = s;
#pragma unroll
      for (int h = 0; h < H; h++) {
        float lg = a_s[s * H + h] + ad_n[h];
        lg = LRELU(lg, 0.2f);
        sw[tid * H + h] = expf(lg - mh[h]) * invd[h];
      }
    }
    __syncthreads();
    for (int j = 0; j < cnt; j++) {
      const int s = ssrc[j];
      const float* hp = hmat + (size_t)s * HC;
#pragma unroll
      for (int q = 0; q < CPT; q++) {
        const int c = tid + q * BD;
        acc[q] += sw[j * H + (c / C)] * hp[c];
      }
    }
  }
#pragma unroll
  for (int q = 0; q < CPT; q++) {
    const int c = tid + q * BD;
    const float v = LRELU(acc[q] + bias[c], act_slope);
    if (BOUT) outb[(size_t)n * HC + c] = __float2bfloat16(v);
    else out[(size_t)n * HC + c] = v;
  }
}

// ---------------- head MLP: 128 -> 16 -> (leaky) 32 -> 2 ----------------
__global__ __launch_bounds__(128) void head_mlp(
    const float* __restrict__ h, const float* __restrict__ pw, const float* __restrict__ pb,
    const float* __restrict__ f1w, const float* __restrict__ f1b,
    const float* __restrict__ f2w, const float* __restrict__ f2b, float* __restrict__ out) {
  const int n = blockIdx.x;
  const int t = threadIdx.x;
  __shared__ float sx[128];
  __shared__ float s1[16];
  __shared__ float s2[32];
  sx[t] = h[(size_t)n * 128 + t];
  __syncthreads();
  if (t < 16) {
    float a = pb[t];
    for (int c = 0; c < 128; c++) a += sx[c] * pw[c * 16 + t];
    s1[t] = a;
  }
  __syncthreads();
  if (t < 32) {
    float a = f1b[t];
    for (int c = 0; c < 16; c++) a += s1[c] * f1w[c * 32 + t];
    s2[t] = LRELU(a, 0.15f);
  }
  __syncthreads();
  if (t < 2) {
    float a = f2b[t];
    for (int c = 0; c < 32; c++) a += s2[c] * f2w[c * 2 + t];
    out[(size_t)n * 2 + t] = a;
  }
}

extern "C" void kernel_launch(void* const* d_in, const int* in_sizes, int n_in,
                              void* d_out, int out_size, void* d_ws, size_t ws_size,
                              hipStream_t stream) {
  const float* x   = (const float*)d_in[0];
  const int* ei    = (const int*)d_in[1];
  const float* W1  = (const float*)d_in[2];
  const float* as1 = (const float*)d_in[3];
  const float* ad1 = (const float*)d_in[4];
  const float* b1  = (const float*)d_in[5];
  const float* W2  = (const float*)d_in[6];
  const float* as2 = (const float*)d_in[7];
  const float* ad2 = (const float*)d_in[8];
  const float* b2  = (const float*)d_in[9];
  const float* W3  = (const float*)d_in[10];
  const float* as3 = (const float*)d_in[11];
  const float* ad3 = (const float*)d_in[12];
  const float* b3  = (const float*)d_in[13];
  const float* pw  = (const float*)d_in[14];
  const float* pb  = (const float*)d_in[15];
  const float* f1w = (const float*)d_in[16];
  const float* f1b = (const float*)d_in[17];
  const float* f2w = (const float*)d_in[18];
  const float* f2b = (const float*)d_in[19];
  float* out = (float*)d_out;

  const int N = in_sizes[0] / 1287;   // 20000
  const int E = in_sizes[1] / 2;      // 160000
  const int Etot = E + N;
  const int* esrc = ei;
  const int* edst = ei + E;
  const int K1 = 1287, K1p = 1312;    // pad to 41*32

  char* ws = (char*)d_ws;
  size_t off = 0;
  auto alloc = [&](size_t bytes) -> void* {
    void* p = ws + off;
    off = (off + bytes + 255) & ~(size_t)255;
    return p;
  };
  float* h_buf  = (float*)alloc((size_t)N * 1024 * sizeof(float));           // GEMM out (fp32)
  float* o_buf  = (float*)alloc((size_t)N * 128 * sizeof(float));            // layer3 out (fp32)
  __hip_bfloat16* xb  = (__hip_bfloat16*)alloc((size_t)N * K1p * 2);         // x bf16 padded
  __hip_bfloat16* ob  = (__hip_bfloat16*)alloc((size_t)N * 1024 * 2);        // inter-layer bf16
  __hip_bfloat16* W1t = (__hip_bfloat16*)alloc((size_t)512 * K1p * 2);
  __hip_bfloat16* W2t = (__hip_bfloat16*)alloc((size_t)1024 * 512 * 2);
  __hip_bfloat16* W3t = (__hip_bfloat16*)alloc((size_t)128 * 1024 * 2);
  float* as_buf  = (float*)alloc((size_t)N * 4 * sizeof(float));
  float* ad_buf  = (float*)alloc((size_t)N * 4 * sizeof(float));
  unsigned* m_buf = (unsigned*)alloc((size_t)N * 4 * sizeof(unsigned));
  float* den_buf = (float*)alloc((size_t)N * 4 * sizeof(float));
  int* deg    = (int*)alloc((size_t)N * sizeof(int));
  int* rowptr = (int*)alloc((size_t)(N + 1) * sizeof(int));
  int* cursor = (int*)alloc((size_t)N * sizeof(int));
  int* csr    = (int*)alloc((size_t)Etot * sizeof(int));

  // ---- CSR build ----
  hipMemsetAsync(deg, 0, (size_t)N * sizeof(int), stream);
  count_deg<<<(E + 255) / 256, 256, 0, stream>>>(edst, E, deg);
  scan_kernel<<<1, 256, 0, stream>>>(deg, rowptr, cursor, N);
  scatter_edges<<<(Etot + 255) / 256, 256, 0, stream>>>(esrc, edst, E, Etot, cursor, csr);

  // ---- casts ----
  {
    const long long nx = (long long)N * K1p;
    cast_pad_rows<<<(int)((nx + 255) / 256), 256, 0, stream>>>(x, xb, N, K1, K1p);
    cast_W_T<<<(512 * K1p + 255) / 256, 256, 0, stream>>>(W1, W1t, K1, 512, K1p);
    cast_W_T<<<(1024 * 512 + 255) / 256, 256, 0, stream>>>(W2, W2t, 512, 1024, 512);
    cast_W_T<<<(128 * 1024 + 255) / 256, 256, 0, stream>>>(W3, W3t, 1024, 128, 1024);
  }

  const int tilesM = (N + 127) / 128;  // 157

  // ---- layer 1: 1287 -> 4x128, concat ----
  {
    const int H = 4, C = 128, HC = 512;
    gemm_bf16<<<tilesM * (HC / 128), 256, 0, stream>>>((const ushort*)xb, (const ushort*)W1t,
                                                       h_buf, N, HC, K1p);
    const int NH = N * H;
    att_dots<<<(NH + 3) / 4, 256, 0, stream>>>(h_buf, as1, ad1, as_buf, ad_buf, NH, H, C);
    hipMemsetAsync(m_buf, 0, (size_t)NH * sizeof(unsigned), stream);
    hipMemsetAsync(den_buf, 0, (size_t)NH * sizeof(float), stream);
    const int tE = Etot * H;
    edge_atomic_max<<<(tE + 255) / 256, 256, 0, stream>>>(esrc, edst, E, Etot, as_buf, ad_buf, m_buf, H);
    edge_atomic_sum<<<(tE + 255) / 256, 256, 0, stream>>>(esrc, edst, E, Etot, as_buf, ad_buf, m_buf, den_buf, H);
    gat_aggregate<4, 128, 2, true><<<N, 256, 0, stream>>>(h_buf, rowptr, csr, as_buf, ad_buf,
                                                          m_buf, den_buf, b1, nullptr, ob, 0.15f);
  }
  // ---- layer 2: 512 -> 4x256, concat ----
  {
    const int H = 4, C = 256, HC = 1024;
    gemm_bf16<<<tilesM * (HC / 128), 256, 0, stream>>>((const ushort*)ob, (const ushort*)W2t,
                                                       h_buf, N, HC, 512);
    const int NH = N * H;
    att_dots<<<(NH + 3) / 4, 256, 0, stream>>>(h_buf, as2, ad2, as_buf, ad_buf, NH, H, C);
    hipMemsetAsync(m_buf, 0, (size_t)NH * sizeof(unsigned), stream);
    hipMemsetAsync(den_buf, 0, (size_t)NH * sizeof(float), stream);
    const int tE = Etot * H;
    edge_atomic_max<<<(tE + 255) / 256, 256, 0, stream>>>(esrc, edst, E, Etot, as_buf, ad_buf, m_buf, H);
    edge_atomic_sum<<<(tE + 255) / 256, 256, 0, stream>>>(esrc, edst, E, Etot, as_buf, ad_buf, m_buf, den_buf, H);
    gat_aggregate<4, 256, 4, true><<<N, 256, 0, stream>>>(h_buf, rowptr, csr, as_buf, ad_buf,
                                                          m_buf, den_buf, b2, nullptr, ob, 0.15f);
  }
  // ---- layer 3: 1024 -> 128, 1 head ----
  {
    const int H = 1, C = 128, HC = 128;
    gemm_bf16<<<tilesM * (HC / 128), 256, 0, stream>>>((const ushort*)ob, (const ushort*)W3t,
                                                       h_buf, N, HC, 1024);
    const int NH = N * H;
    att_dots<<<(NH + 3) / 4, 256, 0, stream>>>(h_buf, as3, ad3, as_buf, ad_buf, NH, H, C);
    hipMemsetAsync(m_buf, 0, (size_t)NH * sizeof(unsigned), stream);
    hipMemsetAsync(den_buf, 0, (size_t)NH * sizeof(float), stream);
    const int tE = Etot * H;
    edge_atomic_max<<<(tE + 255) / 256, 256, 0, stream>>>(esrc, edst, E, Etot, as_buf, ad_buf, m_buf, H);
    edge_atomic_sum<<<(tE + 255) / 256, 256, 0, stream>>>(esrc, edst, E, Etot, as_buf, ad_buf, m_buf, den_buf, H);
    gat_aggregate<1, 128, 1, false><<<N, 128, 0, stream>>>(h_buf, rowptr, csr, as_buf, ad_buf,
                                                           m_buf, den_buf, b3, o_buf, nullptr, 0.15f);
  }
  // ---- head MLP ----
  head_mlp<<<N, 128, 0, stream>>>(o_buf, pw, pb, f1w, f1b, f2w, f2b, out);
}

// Round 3
// 540.268 us; speedup vs baseline: 2.5672x; 1.4727x over previous
//
#include <hip/hip_runtime.h>
#include <hip/hip_bf16.h>
#include <cstdint>
#include <cstddef>

#define LRELU(x, s) ((x) > 0.f ? (x) : (s) * (x))

typedef __attribute__((ext_vector_type(8))) short bf16x8;
typedef __attribute__((ext_vector_type(4))) float f32x4;

__device__ __forceinline__ float bflo(uint v) { return __uint_as_float(v << 16); }
__device__ __forceinline__ float bfhi(uint v) { return __uint_as_float(v & 0xffff0000u); }
__device__ __forceinline__ ushort f2bf(float f) {  // RTNE, finite inputs
  const uint u = __float_as_uint(f);
  return (ushort)((u + 0x7fffu + ((u >> 16) & 1u)) >> 16);
}

// ---------------- casts ----------------
// fp32 [rows][K] -> bf16 [rows][Kp], zero pad K..Kp. 4 elements/thread.
__global__ void cast_pad_rows(const float* __restrict__ in, ushort* __restrict__ out,
                              int rows, int K, int Kp) {
  const int P4 = Kp >> 2;
  const long long idx = (long long)blockIdx.x * blockDim.x + threadIdx.x;
  if (idx >= (long long)rows * P4) return;
  const int r = (int)(idx / P4);
  const int c = ((int)(idx - (long long)r * P4)) << 2;
  const float* p = in + (size_t)r * K + c;
  float v0 = 0.f, v1 = 0.f, v2 = 0.f, v3 = 0.f;
  if (c + 3 < K) { v0 = p[0]; v1 = p[1]; v2 = p[2]; v3 = p[3]; }
  else {
    if (c + 0 < K) v0 = p[0];
    if (c + 1 < K) v1 = p[1];
    if (c + 2 < K) v2 = p[2];
    if (c + 3 < K) v3 = p[3];
  }
  uint2 o;
  o.x = (uint)f2bf(v0) | ((uint)f2bf(v1) << 16);
  o.y = (uint)f2bf(v2) | ((uint)f2bf(v3) << 16);
  *(uint2*)(out + (size_t)r * Kp + c) = o;
}

// W fp32 [K][Nn] -> Wt bf16 [Nn][Kp] transposed, zero pad. 32x32 LDS tile.
__global__ void cast_W_T(const float* __restrict__ W, ushort* __restrict__ Wt,
                         int K, int Nn, int Kp) {
  __shared__ float tile[32][33];
  const int kt = blockIdx.x * 32;
  const int nt = blockIdx.y * 32;
  const int tx = threadIdx.x;   // 0..31
  const int ty = threadIdx.y;   // 0..7
  for (int r = ty; r < 32; r += 8) {
    const int k = kt + r, nn = nt + tx;
    tile[r][tx] = (k < K && nn < Nn) ? W[(size_t)k * Nn + nn] : 0.f;
  }
  __syncthreads();
  for (int r = ty; r < 32; r += 8) {
    const int nn = nt + r, k = kt + tx;
    if (nn < Nn && k < Kp) Wt[(size_t)nn * Kp + k] = f2bf(tile[tx][r]);
  }
}

// ---------------- bf16 MFMA GEMM: C[M,N] bf16 = A[M,Kp] bf16 @ Bt[N,Kp]^T ----------------
__global__ __launch_bounds__(256) void gemm_bf16(
    const ushort* __restrict__ A, const ushort* __restrict__ Bt, ushort* __restrict__ C,
    int M, int N, int Kp) {
  constexpr int LDA = 40;  // 32 + 8 pad
  __shared__ ushort sA[128 * LDA];
  __shared__ ushort sB[128 * LDA];
  const int tid = threadIdx.x;
  const int wave = tid >> 6;
  const int lane = tid & 63;
  const int tilesN = N >> 7;
  const int bx = blockIdx.x % tilesN;
  const int by = blockIdx.x / tilesN;
  const int srow = tid >> 2;
  const int sseg = (tid & 3) * 8;
  const int wrow = (wave >> 1) * 64;
  const int wcol = (wave & 1) * 64;
  const int quad = lane >> 4;
  const int ml = lane & 15;

  const int rA1 = min(by * 128 + srow, M - 1);
  const int rA2 = min(by * 128 + srow + 64, M - 1);
  const int cB1 = bx * 128 + srow;
  const size_t offA1 = (size_t)rA1 * Kp + sseg;
  const size_t offA2 = (size_t)rA2 * Kp + sseg;
  const size_t offB1 = (size_t)cB1 * Kp + sseg;
  const size_t offB2 = (size_t)(cB1 + 64) * Kp + sseg;

  f32x4 acc[4][4];
#pragma unroll
  for (int mi = 0; mi < 4; mi++)
#pragma unroll
    for (int ni = 0; ni < 4; ni++)
#pragma unroll
      for (int e = 0; e < 4; e++) acc[mi][ni][e] = 0.f;

  for (int k0 = 0; k0 < Kp; k0 += 32) {
    const uint4 a1 = *(const uint4*)(A + offA1 + k0);
    const uint4 a2 = *(const uint4*)(A + offA2 + k0);
    const uint4 b1 = *(const uint4*)(Bt + offB1 + k0);
    const uint4 b2 = *(const uint4*)(Bt + offB2 + k0);
    __syncthreads();
    *(uint4*)&sA[srow * LDA + sseg] = a1;
    *(uint4*)&sA[(srow + 64) * LDA + sseg] = a2;
    *(uint4*)&sB[srow * LDA + sseg] = b1;
    *(uint4*)&sB[(srow + 64) * LDA + sseg] = b2;
    __syncthreads();
    bf16x8 af[4], bfr[4];
#pragma unroll
    for (int mi = 0; mi < 4; mi++)
      af[mi] = *(const bf16x8*)&sA[(wrow + mi * 16 + ml) * LDA + quad * 8];
#pragma unroll
    for (int ni = 0; ni < 4; ni++)
      bfr[ni] = *(const bf16x8*)&sB[(wcol + ni * 16 + ml) * LDA + quad * 8];
#pragma unroll
    for (int mi = 0; mi < 4; mi++)
#pragma unroll
      for (int ni = 0; ni < 4; ni++)
        acc[mi][ni] = __builtin_amdgcn_mfma_f32_16x16x32_bf16(af[mi], bfr[ni], acc[mi][ni], 0, 0, 0);
  }

#pragma unroll
  for (int mi = 0; mi < 4; mi++) {
#pragma unroll
    for (int r = 0; r < 4; r++) {
      const int row = by * 128 + wrow + mi * 16 + quad * 4 + r;
      if (row < M) {
#pragma unroll
        for (int ni = 0; ni < 4; ni++) {
          const int col = bx * 128 + wcol + ni * 16 + ml;
          C[(size_t)row * N + col] = f2bf(acc[mi][ni][r]);
        }
      }
    }
  }
}

// ---------------- CSR build ----------------
__global__ void count_deg(const int* __restrict__ dst, int E, int* __restrict__ deg) {
  const int t = blockIdx.x * blockDim.x + threadIdx.x;
  if (t < E) atomicAdd(&deg[dst[t]], 1);
}

// single-block scan, wave-shuffle based. block = 1024.
__global__ __launch_bounds__(1024) void scan_kernel(const int* __restrict__ deg,
                                                    int* __restrict__ rowptr,
                                                    int* __restrict__ cursor, int n) {
  __shared__ int swsum[16];
  __shared__ int carry_s;
  const int t = threadIdx.x;
  const int wv = t >> 6, lane = t & 63;
  if (t == 0) carry_s = 0;
  __syncthreads();
  for (int base = 0; base < n; base += 1024) {
    const int i = base + t;
    const int v = (i < n) ? (deg[i] + 1) : 0;
    int sc = v;
#pragma unroll
    for (int off = 1; off < 64; off <<= 1) {
      const int u = __shfl_up(sc, off);
      if (lane >= off) sc += u;
    }
    if (lane == 63) swsum[wv] = sc;
    __syncthreads();
    if (t < 16) {
      int x = swsum[t];
#pragma unroll
      for (int off = 1; off < 16; off <<= 1) {
        const int u = __shfl_up(x, off);
        if (t >= off) x += u;
      }
      swsum[t] = x;
    }
    __syncthreads();
    const int incl = sc + (wv == 0 ? 0 : swsum[wv - 1]) + carry_s;
    if (i < n) { rowptr[i + 1] = incl; cursor[i] = incl - v; }
    if (base == 0 && t == 0) rowptr[0] = 0;
    __syncthreads();
    if (t == 0) carry_s += swsum[15];
    __syncthreads();
  }
}

__global__ void scatter_edges(const int* __restrict__ esrc, const int* __restrict__ edst,
                              int E, int Etot, int* __restrict__ cursor,
                              int* __restrict__ csr_src) {
  const int t = blockIdx.x * blockDim.x + threadIdx.x;
  if (t >= Etot) return;
  int s, d;
  if (t < E) { s = esrc[t]; d = edst[t]; } else { s = t - E; d = s; }
  const int pos = atomicAdd(&cursor[d], 1);
  csr_src[pos] = s;
}

// ---------------- attention dots (bf16 h) ----------------
template <int H, int C>
__global__ void att_dots_b(const ushort* __restrict__ hb, const float* __restrict__ att_s,
                           const float* __restrict__ att_d, float* __restrict__ a_s,
                           float* __restrict__ a_d, int NH) {
  const int w = blockIdx.x * (blockDim.x >> 6) + (threadIdx.x >> 6);
  const int lane = threadIdx.x & 63;
  if (w >= NH) return;
  const int n = w / H;
  const int h = w - n * H;
  const uint* hp = (const uint*)(hb + (size_t)n * (H * C) + h * C);
  const float2* asp = (const float2*)(att_s + h * C);
  const float2* adp = (const float2*)(att_d + h * C);
  float ss = 0.f, sd = 0.f;
#pragma unroll
  for (int p = lane; p < C / 2; p += 64) {
    const uint v = hp[p];
    const float x0 = bflo(v), x1 = bfhi(v);
    const float2 a = asp[p], b = adp[p];
    ss += x0 * a.x + x1 * a.y;
    sd += x0 * b.x + x1 * b.y;
  }
  for (int off = 32; off > 0; off >>= 1) {
    ss += __shfl_down(ss, off);
    sd += __shfl_down(sd, off);
  }
  if (lane == 0) { a_s[w] = ss; a_d[w] = sd; }
}

// ---------------- fused aggregate: softmax-weighted gather, bf16 in/out ----------------
// out[n,:] = lrelu( (sum_j w_j * h[src_j,:]) / (sum_j w_j) + bias ), w_j = exp(lrelu(a_s+a_d))
template <int H, int C, int TPB, int PPT>
__global__ __launch_bounds__(TPB) void gat_aggregate_b(
    const ushort* __restrict__ hb, const int* __restrict__ rowptr,
    const int* __restrict__ csr_src, const float* __restrict__ a_s,
    const float* __restrict__ a_d, const float* __restrict__ bias,
    ushort* __restrict__ outb, float act_slope) {
  constexpr int HC = H * C;
  constexpr int CH = C / 2;  // bf16 pairs per head
  constexpr int TILE = 32;
  const int n = blockIdx.x;
  const int tid = threadIdx.x;
  __shared__ int ssrc[TILE];
  __shared__ float sw[TILE * H];
  __shared__ float sden[H];
  if (tid < H) sden[tid] = 0.f;
  float ad_n[H];
#pragma unroll
  for (int h = 0; h < H; h++) ad_n[h] = a_d[n * H + h];
  const int start = rowptr[n], end = rowptr[n + 1];
  float2 acc[PPT];
#pragma unroll
  for (int q = 0; q < PPT; q++) acc[q] = make_float2(0.f, 0.f);

  for (int base = start; base < end; base += TILE) {
    const int cnt = min(TILE, end - base);
    __syncthreads();
    if (tid < cnt) {
      const int s = csr_src[base + tid];
      ssrc[tid] = s;
      float asv[H];
      if constexpr (H == 4) {
        const float4 t4 = *(const float4*)(a_s + s * 4);
        asv[0] = t4.x; asv[1] = t4.y; asv[2] = t4.z; asv[3] = t4.w;
      } else {
#pragma unroll
        for (int h = 0; h < H; h++) asv[h] = a_s[s * H + h];
      }
#pragma unroll
      for (int h = 0; h < H; h++) {
        float lg = asv[h] + ad_n[h];
        lg = LRELU(lg, 0.2f);
        const float w = __expf(lg);
        sw[tid * H + h] = w;
        atomicAdd(&sden[h], w);
      }
    }
    __syncthreads();
    for (int j = 0; j < cnt; j++) {
      const uint* hp = (const uint*)(hb + (size_t)ssrc[j] * HC);
      const float* swj = &sw[j * H];
#pragma unroll
      for (int q = 0; q < PPT; q++) {
        const int p = tid + q * TPB;
        const float w = swj[p / CH];
        const uint v = hp[p];
        acc[q].x += w * bflo(v);
        acc[q].y += w * bfhi(v);
      }
    }
  }
  __syncthreads();
  if (tid < H) sden[tid] = 1.f / sden[tid];
  __syncthreads();
#pragma unroll
  for (int q = 0; q < PPT; q++) {
    const int p = tid + q * TPB;
    const float iv = sden[p / CH];
    const float2 b2 = *(const float2*)(bias + 2 * p);
    const float v0 = LRELU(acc[q].x * iv + b2.x, act_slope);
    const float v1 = LRELU(acc[q].y * iv + b2.y, act_slope);
    ((uint*)outb)[(size_t)n * (HC / 2) + p] = (uint)f2bf(v0) | ((uint)f2bf(v1) << 16);
  }
}

// ---------------- layer-3 aggregate (H=1,C=128) fused with head MLP ----------------
__global__ __launch_bounds__(64) void gat_agg3_mlp(
    const ushort* __restrict__ hb, const int* __restrict__ rowptr,
    const int* __restrict__ csr_src, const float* __restrict__ a_s,
    const float* __restrict__ a_d, const float* __restrict__ b3,
    const float* __restrict__ pw, const float* __restrict__ pb,
    const float* __restrict__ f1w, const float* __restrict__ f1b,
    const float* __restrict__ f2w, const float* __restrict__ f2b,
    float* __restrict__ out) {
  constexpr int TILE = 32;
  const int n = blockIdx.x;
  const int tid = threadIdx.x;  // 0..63, pair p = tid -> channels 2p,2p+1
  __shared__ int ssrc[TILE];
  __shared__ float sw[TILE];
  __shared__ float sden1;
  __shared__ float sx[128];
  __shared__ float s1[16];
  __shared__ float s2[32];
  if (tid == 0) sden1 = 0.f;
  const float ad_n = a_d[n];
  const int start = rowptr[n], end = rowptr[n + 1];
  float2 acc = make_float2(0.f, 0.f);
  for (int base = start; base < end; base += TILE) {
    const int cnt = min(TILE, end - base);
    __syncthreads();
    if (tid < cnt) {
      const int s = csr_src[base + tid];
      ssrc[tid] = s;
      float lg = a_s[s] + ad_n;
      lg = LRELU(lg, 0.2f);
      const float w = __expf(lg);
      sw[tid] = w;
      atomicAdd(&sden1, w);
    }
    __syncthreads();
    for (int j = 0; j < cnt; j++) {
      const uint v = ((const uint*)(hb + (size_t)ssrc[j] * 128))[tid];
      const float w = sw[j];
      acc.x += w * bflo(v);
      acc.y += w * bfhi(v);
    }
  }
  __syncthreads();
  const float iv = 1.f / sden1;
  sx[2 * tid]     = LRELU(acc.x * iv + b3[2 * tid], 0.15f);
  sx[2 * tid + 1] = LRELU(acc.y * iv + b3[2 * tid + 1], 0.15f);
  __syncthreads();
  if (tid < 16) {
    float a = pb[tid];
    for (int c = 0; c < 128; c++) a += sx[c] * pw[c * 16 + tid];
    s1[tid] = a;
  }
  __syncthreads();
  if (tid < 32) {
    float a = f1b[tid];
    for (int c = 0; c < 16; c++) a += s1[c] * f1w[c * 32 + tid];
    s2[tid] = LRELU(a, 0.15f);
  }
  __syncthreads();
  if (tid < 2) {
    float a = f2b[tid];
    for (int c = 0; c < 32; c++) a += s2[c] * f2w[c * 2 + tid];
    out[(size_t)n * 2 + tid] = a;
  }
}

extern "C" void kernel_launch(void* const* d_in, const int* in_sizes, int n_in,
                              void* d_out, int out_size, void* d_ws, size_t ws_size,
                              hipStream_t stream) {
  const float* x   = (const float*)d_in[0];
  const int* ei    = (const int*)d_in[1];
  const float* W1  = (const float*)d_in[2];
  const float* as1 = (const float*)d_in[3];
  const float* ad1 = (const float*)d_in[4];
  const float* b1  = (const float*)d_in[5];
  const float* W2  = (const float*)d_in[6];
  const float* as2 = (const float*)d_in[7];
  const float* ad2 = (const float*)d_in[8];
  const float* b2  = (const float*)d_in[9];
  const float* W3  = (const float*)d_in[10];
  const float* as3 = (const float*)d_in[11];
  const float* ad3 = (const float*)d_in[12];
  const float* b3  = (const float*)d_in[13];
  const float* pw  = (const float*)d_in[14];
  const float* pb  = (const float*)d_in[15];
  const float* f1w = (const float*)d_in[16];
  const float* f1b = (const float*)d_in[17];
  const float* f2w = (const float*)d_in[18];
  const float* f2b = (const float*)d_in[19];
  float* out = (float*)d_out;

  const int N = in_sizes[0] / 1287;   // 20000
  const int E = in_sizes[1] / 2;      // 160000
  const int Etot = E + N;
  const int* esrc = ei;
  const int* edst = ei + E;
  const int K1 = 1287, K1p = 1312;

  char* ws = (char*)d_ws;
  size_t off = 0;
  auto alloc = [&](size_t bytes) -> void* {
    void* p = ws + off;
    off = (off + bytes + 255) & ~(size_t)255;
    return p;
  };
  ushort* hb  = (ushort*)alloc((size_t)N * 1024 * 2);   // GEMM out (bf16)
  ushort* ob  = (ushort*)alloc((size_t)N * 1024 * 2);   // aggregate out (bf16)
  ushort* xb  = (ushort*)alloc((size_t)N * K1p * 2);
  ushort* W1t = (ushort*)alloc((size_t)512 * K1p * 2);
  ushort* W2t = (ushort*)alloc((size_t)1024 * 512 * 2);
  ushort* W3t = (ushort*)alloc((size_t)128 * 1024 * 2);
  float* as_buf = (float*)alloc((size_t)N * 4 * sizeof(float));
  float* ad_buf = (float*)alloc((size_t)N * 4 * sizeof(float));
  int* deg    = (int*)alloc((size_t)N * sizeof(int));
  int* rowptr = (int*)alloc((size_t)(N + 1) * sizeof(int));
  int* cursor = (int*)alloc((size_t)N * sizeof(int));
  int* csr    = (int*)alloc((size_t)Etot * sizeof(int));

  // ---- CSR build ----
  hipMemsetAsync(deg, 0, (size_t)N * sizeof(int), stream);
  count_deg<<<(E + 255) / 256, 256, 0, stream>>>(edst, E, deg);
  scan_kernel<<<1, 1024, 0, stream>>>(deg, rowptr, cursor, N);
  scatter_edges<<<(Etot + 255) / 256, 256, 0, stream>>>(esrc, edst, E, Etot, cursor, csr);

  // ---- casts ----
  {
    const long long nx = (long long)N * (K1p / 4);
    cast_pad_rows<<<(int)((nx + 255) / 256), 256, 0, stream>>>(x, xb, N, K1, K1p);
    cast_W_T<<<dim3(K1p / 32, (512 + 31) / 32), dim3(32, 8), 0, stream>>>(W1, W1t, K1, 512, K1p);
    cast_W_T<<<dim3(512 / 32, 1024 / 32), dim3(32, 8), 0, stream>>>(W2, W2t, 512, 1024, 512);
    cast_W_T<<<dim3(1024 / 32, 128 / 32), dim3(32, 8), 0, stream>>>(W3, W3t, 1024, 128, 1024);
  }

  const int tilesM = (N + 127) / 128;  // 157

  // ---- layer 1: 1287 -> 4x128, concat ----
  {
    const int H = 4, C = 128, HC = 512;
    gemm_bf16<<<tilesM * (HC / 128), 256, 0, stream>>>(xb, W1t, hb, N, HC, K1p);
    const int NH = N * H;
    att_dots_b<4, 128><<<(NH + 3) / 4, 256, 0, stream>>>(hb, as1, ad1, as_buf, ad_buf, NH);
    gat_aggregate_b<4, 128, 256, 1><<<N, 256, 0, stream>>>(hb, rowptr, csr, as_buf, ad_buf,
                                                           b1, ob, 0.15f);
  }
  // ---- layer 2: 512 -> 4x256, concat ----
  {
    const int H = 4, C = 256, HC = 1024;
    gemm_bf16<<<tilesM * (HC / 128), 256, 0, stream>>>(ob, W2t, hb, N, HC, 512);
    const int NH = N * H;
    att_dots_b<4, 256><<<(NH + 3) / 4, 256, 0, stream>>>(hb, as2, ad2, as_buf, ad_buf, NH);
    gat_aggregate_b<4, 256, 256, 2><<<N, 256, 0, stream>>>(hb, rowptr, csr, as_buf, ad_buf,
                                                           b2, ob, 0.15f);
  }
  // ---- layer 3: 1024 -> 128, 1 head + head MLP fused ----
  {
    const int HC = 128;
    gemm_bf16<<<tilesM * (HC / 128), 256, 0, stream>>>(ob, W3t, hb, N, HC, 1024);
    att_dots_b<1, 128><<<(N + 3) / 4, 256, 0, stream>>>(hb, as3, ad3, as_buf, ad_buf, N);
    gat_agg3_mlp<<<N, 64, 0, stream>>>(hb, rowptr, csr, as_buf, ad_buf, b3,
                                       pw, pb, f1w, f1b, f2w, f2b, out);
  }
}